// Round 14
// baseline (205.259 us; speedup 1.0000x reference)
//
#include <hip/hip_runtime.h>
#include <hip/hip_fp16.h>
#include <math.h>

typedef __attribute__((ext_vector_type(8))) short bf16x8;
typedef __attribute__((ext_vector_type(8))) _Float16 half8;
typedef __attribute__((ext_vector_type(4))) float f32x4;
typedef __attribute__((ext_vector_type(4))) int int4v;

#define GL_LDS16(g, l) __builtin_amdgcn_global_load_lds( \
    (const __attribute__((address_space(1))) void*)(g), \
    (__attribute__((address_space(3))) void*)(l), 16, 0, 0)

__device__ __forceinline__ ushort f2bf(float f) {
    union { float f; unsigned u; } v; v.f = f;
    unsigned r = (v.u + 0x7fffu + ((v.u >> 16) & 1u)) >> 16;
    return (ushort)r;
}
__device__ __forceinline__ float bf2f(ushort h) {
    union { unsigned u; float f; } v; v.u = ((unsigned)h) << 16;
    return v.f;
}

// ---------------------------------------------------------------------------
// Weight prepack helper: w[oc][cin][3][3] -> wp[cc][kk][kg][CoutP][8]
__device__ __forceinline__ void prep_one(const float* __restrict__ w,
        ushort* __restrict__ wp, int u, int Cin, int CoutR, int CoutP) {
    int oc = u % CoutP; int t = u / CoutP;
    int kg = t & 3; t >>= 2;
    int kk = t % 9; int cc = t / 9;
    alignas(16) ushort tmp[8];
    for (int j = 0; j < 8; ++j) {
        int c = cc * 32 + kg * 8 + j;
        float v = (oc < CoutR) ? w[((size_t)oc * Cin + c) * 9 + kk] : 0.f;
        tmp[j] = f2bf(v);
    }
    *(int4v*)(wp + (size_t)u * 8) = *(int4v*)tmp;
}

// ---------------------------------------------------------------------------
// Fused packs + prepack:
//  z=0: pack concat(src0,src1)->xin1[px][128] (bf16) AND xg1[b][g][px][8] (f16)
//  z=1: up2(l_off)*2 -> xin2[px][64:128]; z=2: up2(l_fea) -> xin4[px][64:128]
//  z=3: all weight prepacks (wd -> f16) + om bias permute + zero guard
__global__ __launch_bounds__(256) void pack_combo_k(
        const float* __restrict__ s0, const float* __restrict__ s1,
        const float* __restrict__ lo, const float* __restrict__ lf,
        const float* __restrict__ w1, const float* __restrict__ w2,
        const float* __restrict__ w3, const float* __restrict__ wom,
        const float* __restrict__ wd, const float* __restrict__ wf,
        const float* __restrict__ bom,
        ushort* __restrict__ xin1, ushort* __restrict__ xin2,
        ushort* __restrict__ xin4, ushort* __restrict__ xg1,
        ushort* __restrict__ w1p, ushort* __restrict__ w2p,
        ushort* __restrict__ w3p, ushort* __restrict__ womp,
        ushort* __restrict__ wdp, ushort* __restrict__ wfp,
        float* __restrict__ bpp, float* __restrict__ zg) {
    int b = blockIdx.y;
    int z = blockIdx.z;
    int px = blockIdx.x * 64 + (threadIdx.x & 63);
    int u = threadIdx.x >> 6;
    if (z == 0) {
        for (int half = 0; half < 2; ++half) {
            int cg = u + half * 4;
            float vals[16];
            alignas(16) ushort tmp[16];
            for (int i = 0; i < 16; ++i) {
                int c = cg * 16 + i;
                float v = (c < 64) ? s0[((size_t)(b * 64 + c)) * 9216 + px]
                                   : s1[((size_t)(b * 64 + c - 64)) * 9216 + px];
                vals[i] = v;
                tmp[i] = f2bf(v);
            }
            ushort* dst = xin1 + ((size_t)(b * 9216) + px) * 128 + cg * 16;
            *(int4v*)dst = *(int4v*)&tmp[0];
            *(int4v*)(dst + 8) = *(int4v*)&tmp[8];
            if (half == 0) {
                // gather copy in f16: groups g = cg*2, cg*2+1
                alignas(16) __half th[16];
                for (int i = 0; i < 16; ++i) th[i] = __float2half(vals[i]);
                ushort* gdst = xg1 + (((size_t)(b * 8 + cg * 2) * 9216) + px) * 8;
                *(int4v*)gdst = *(int4v*)&th[0];
                *(int4v*)(gdst + 9216 * 8) = *(int4v*)&th[8];
            }
        }
    } else if (z < 3) {
        const float* in = (z == 1) ? lo : lf;
        float scale = (z == 1) ? 2.0f : 1.0f;
        ushort* xo = (z == 1) ? xin2 : xin4;
        int y = px / 96, x = px % 96;
        float sy = fmaxf(y * 0.5f - 0.25f, 0.f);
        float sx = fmaxf(x * 0.5f - 0.25f, 0.f);
        int y0 = (int)sy, x0 = (int)sx;
        float ty = sy - (float)y0, tx = sx - (float)x0;
        int y1 = min(y0 + 1, 47), x1 = min(x0 + 1, 47);
        alignas(16) ushort tmp[16];
        for (int i = 0; i < 16; ++i) {
            int c = u * 16 + i;
            const float* p = in + ((size_t)(b * 64 + c)) * 2304;
            float v00 = p[y0 * 48 + x0], v01 = p[y0 * 48 + x1];
            float v10 = p[y1 * 48 + x0], v11 = p[y1 * 48 + x1];
            float v = (v00 * (1.f - tx) + v01 * tx) * (1.f - ty)
                    + (v10 * (1.f - tx) + v11 * tx) * ty;
            tmp[i] = f2bf(v * scale);
        }
        ushort* dst = xo + ((size_t)(b * 9216) + px) * 128 + 64 + u * 16;
        *(int4v*)dst = *(int4v*)&tmp[0];
        *(int4v*)(dst + 8) = *(int4v*)&tmp[8];
    } else {
        // prepack: 57904 units over 576 blocks
        int uu = (blockIdx.x + 144 * blockIdx.y) * 256 + threadIdx.x;
        if (uu < 9216) prep_one(w1, w1p, uu, 128, 64, 64);
        else if (uu < 18432) prep_one(w2, w2p, uu - 9216, 128, 64, 64);
        else if (uu < 23040) prep_one(w3, w3p, uu - 18432, 64, 64, 64);
        else if (uu < 43776) {
            // om conv, permuted: CoutP=288, oc p = gkk*4 + t3 (t3==3 -> pad)
            int v = uu - 23040;               // units = 2*9*4*288 = 20736
            int ocp = v % 288; int t = v / 288;
            int kg = t & 3; t >>= 2;
            int kk = t % 9; int cc = t / 9;
            int t3 = ocp & 3, gkkp = ocp >> 2;
            alignas(16) ushort tmp[8];
            for (int j = 0; j < 8; ++j) {
                int c = cc * 32 + kg * 8 + j;
                float vv = (t3 < 3)
                    ? wom[((size_t)(t3 * 72 + gkkp) * 64 + c) * 9 + kk] : 0.f;
                tmp[j] = f2bf(vv);
            }
            *(int4v*)(womp + (size_t)v * 8) = *(int4v*)tmp;
        } else if (uu < 48384) {
            int v = uu - 43776;               // wd -> f16 [gkk*64 + oc][8]
            int oc = v & 63; int gkk = v >> 6;
            int g = gkk / 9, kk = gkk % 9;
            alignas(16) __half tmp[8];
            for (int j = 0; j < 8; ++j)
                tmp[j] = __float2half(wd[((size_t)oc * 64 + g * 8 + j) * 9 + kk]);
            *(int4v*)(wdp + (size_t)v * 8) = *(int4v*)tmp;
        } else if (uu < 57600) prep_one(wf, wfp, uu - 48384, 128, 64, 64);
        else if (uu < 57888) {
            int ocp = uu - 57600; int t3 = ocp & 3, gkkp = ocp >> 2;
            bpp[ocp] = (t3 < 3) ? bom[t3 * 72 + gkkp] : 0.f;
        } else if (uu < 57904) zg[uu - 57888] = 0.f;  // 64-B zero guard
    }
}

// ---------------------------------------------------------------------------
// MFMA 3x3 conv: per-wave MT*16 oc x 16 px, block = 8x8 px tile.
// Activation staged in 64-channel slices via global_load_lds; zero-guard for
// pad/OOB. CIN=64: single stage (one barrier). CIN=128: 2 slices dbuf.
// A-fragments read directly from global prepacked weights (L1-hot).
template<int CIN, int MT, int NZ, bool LRELU, bool ST_F32, bool ST_CHL>
__global__ __launch_bounds__(256, 4) void conv_mfma_k(
        const ushort* __restrict__ xin,      // [b][9216][CIN] bf16
        const ushort* __restrict__ wp,       // [CIN/32][9][4][CoutP][8]
        const float* __restrict__ bias,
        float* __restrict__ outf,            // NCHW fp32
        ushort* __restrict__ chl,            // ch-last bf16
        const ushort* __restrict__ zg,       // 64-B zero guard
        int CoutR, int CoutP, int ochs, int ocoff) {
    constexpr int SL = CIN / 64;
    constexpr int OCN = MT * 16;
    __shared__ ushort s_act[SL][7200];        // [buf][100 rows x 72u] 14.4 KB each

    int tid = threadIdx.x;
    int wv = tid >> 6, ln = tid & 63;
    int l15 = ln & 15, l4 = ln >> 4;

    constexpr int TOTAL = 144 * 4 * NZ;
    constexpr int CHUNK = TOTAL / 8;
    int bid = blockIdx.x;
    int nid = (bid & 7) * CHUNK + (bid >> 3);
    int zc = nid % NZ; int r1 = nid / NZ;
    int tile = r1 % 144; int b = r1 / 144;    // b-major banding
    int bx = (tile % 12) * 8, by = (tile / 12) * 8;
    int oc0 = zc * OCN;

    int px_l = wv * 16 + l15;                 // px in 8x8 tile
    int py = px_l >> 3, pxx = px_l & 7;
    int b_base = (py * 10 + pxx) * 72 + l4 * 8;

    const ushort* wlane = wp + ((size_t)l4 * CoutP + oc0 + l15) * 8;

    f32x4 acc[MT];
#pragma unroll
    for (int mt = 0; mt < MT; ++mt) acc[mt] = (f32x4){0.f, 0.f, 0.f, 0.f};

    auto STAGE = [&](int sl, int buf) {
        for (int i = tid; i < 900; i += 256) {
            int p = i / 9, q = i - p * 9;     // q==8 -> pad slot
            int gy = by + (p / 10) - 1, gx = bx + (p % 10) - 1;
            const ushort* src = zg;
            if (q < 8 && (unsigned)gy < 96u && (unsigned)gx < 96u)
                src = xin + ((size_t)(b * 9216 + gy * 96 + gx) * CIN
                             + sl * 64 + q * 8);
            GL_LDS16(src, s_act[buf] + (size_t)i * 8);
        }
    };

    STAGE(0, 0);
    __syncthreads();
#pragma unroll
    for (int sl = 0; sl < SL; ++sl) {
        if (sl + 1 < SL) STAGE(sl + 1, (sl + 1) & 1);
#pragma unroll
        for (int cc2 = 0; cc2 < 2; ++cc2) {
#pragma unroll
            for (int kk = 0; kk < 9; ++kk) {
                bf16x8 bfrag = *(const bf16x8*)(s_act[sl & (SL - 1)] + b_base +
                                   ((kk / 3) * 10 + (kk % 3)) * 72 + cc2 * 32);
#pragma unroll
                for (int mt = 0; mt < MT; ++mt) {
                    bf16x8 af = *(const bf16x8*)(wlane +
                        ((size_t)((sl * 2 + cc2) * 36 + kk * 4) * CoutP + mt * 16) * 8);
                    acc[mt] = __builtin_amdgcn_mfma_f32_16x16x32_bf16(
                        af, bfrag, acc[mt], 0, 0, 0);
                }
            }
        }
        if (sl + 1 < SL) __syncthreads();
    }

    int gy = by + py, gx = bx + pxx;
    size_t pxg = (size_t)b * 9216 + gy * 96 + gx;
#pragma unroll
    for (int mt = 0; mt < MT; ++mt) {
        int ocb = oc0 + mt * 16 + l4 * 4;
        ushort hb[4];
#pragma unroll
        for (int r = 0; r < 4; ++r) {
            int oc = ocb + r;
            float v = acc[mt][r] + ((oc < CoutR) ? bias[oc] : 0.f);
            if (LRELU) v = (v >= 0.f) ? v : 0.1f * v;
            hb[r] = f2bf(v);
            if (ST_F32 && oc < CoutR)
                outf[((size_t)b * CoutR + oc) * 9216 + gy * 96 + gx] = v;
        }
        if (ST_CHL && ocb < CoutR) {
            uint2 pk;
            pk.x = (uint)hb[0] | ((uint)hb[1] << 16);
            pk.y = (uint)hb[2] | ((uint)hb[3] << 16);
            *(uint2*)(chl + pxg * ochs + ocoff + ocb) = pk;
        }
    }
}

// ---------------------------------------------------------------------------
// Fused om-conv + DCNv2, 3-way split-K, 32-px band (2 px-groups/wave).
// Every weight A-fragment (womp and wdp) is loaded ONCE and used for BOTH
// px-groups' B-fragments -> per-px weight L2 traffic halves vs r13.
// Per step s: om C-tiles for both groups (18 af, 36 MFMA) -> PREP both
// groups (issue 8 gathers) -> consume step s-1 (lerp + 8 PV MFMA, 4 shared
// wdp af loads). grid = 1152 x 192 thr.
__global__ __launch_bounds__(192, 2) void dcn_fused_k(
        const ushort* __restrict__ xoff,     // [b][px][64] ch-last bf16
        const ushort* __restrict__ xg1,      // [b][8][9216][8] f16
        const ushort* __restrict__ womp,     // [cc][kk][4][288][8] bf16
        const float* __restrict__ bpp,       // permuted om bias [288]
        const ushort* __restrict__ wdp,      // f16 [gkk*64+oc][8]
        const float* __restrict__ bd, ushort* __restrict__ chl,
        const ushort* __restrict__ zg) {
    __shared__ ushort s_x[816 * 8];           // 3 rows x 34 cols x 64 ch, 13 KB
    __shared__ float s_red[2][2][64][17];     // 17.4 KB
    int tid = threadIdx.x;
    int kq = tid >> 6, ln = tid & 63;
    int l15 = ln & 15, l4 = ln >> 4;
    int bid = blockIdx.x;                     // 0..1151
    int nid = (bid & 7) * 144 + (bid >> 3);   // XCD-chunked swizzle
    int pxb = nid % 288; int b = nid / 288;   // b-major banding
    int px0 = pxb * 32;
    int y = px0 / 96, x0 = px0 % 96;          // x0 in {0,32,64}

    // ---- stage xoff halo band (rows y-1..y+1, cols x0-1..x0+32) ----
    for (int i = tid; i < 816; i += 192) {
        int P = i >> 3, s8 = i & 7;
        int q = s8 ^ (P & 7);                 // inverse-swizzled source chunk
        int ry = y - 1 + P / 34, rx = x0 - 1 + P % 34;
        const ushort* src = zg;
        if ((unsigned)ry < 96u && (unsigned)rx < 96u)
            src = xoff + (((size_t)b * 9216 + ry * 96 + rx) * 64 + q * 8);
        GL_LDS16(src, s_x + (size_t)i * 8);
    }
    __syncthreads();

    f32x4 acc0[4], acc1[4];
#pragma unroll
    for (int mt = 0; mt < 4; ++mt) {
        acc0[mt] = (f32x4){0.f, 0.f, 0.f, 0.f};
        acc1[mt] = (f32x4){0.f, 0.f, 0.f, 0.f};
    }

    int4v Ab[2][2][4];                        // [parity][group][corner]
    float cwb[2][2][4];

    // address calc + gather ISSUE for (step s, group gx)
    auto PREP = [&](int s, int gx, const f32x4& aom, int4v* A, float* cw) {
        int st = kq * 6 + s;
        int gkk = st * 4 + l4;
        int g = gkk / 9, kk = gkk - g * 9;
        int bofs = st * 16 + l4 * 4;
        int xx = x0 + gx * 16 + l15;
        float oy = aom[0] + bpp[bofs];
        float ox = aom[1] + bpp[bofs + 1];
        float mm = 1.f / (1.f + __expf(-(aom[2] + bpp[bofs + 2])));
        float py = oy + (float)(y + kk / 3 - 1);
        float pxf = ox + (float)(xx + kk % 3 - 1);
        float yf = floorf(py), xf = floorf(pxf);
        float fy = py - yf, fx = pxf - xf;
        int iy0 = (int)yf, ix0 = (int)xf;
        int iy1 = iy0 + 1, ix1 = ix0 + 1;
        float vy0 = ((unsigned)iy0 < 96u) ? 1.f : 0.f;
        float vy1 = ((unsigned)iy1 < 96u) ? 1.f : 0.f;
        float vx0 = ((unsigned)ix0 < 96u) ? 1.f : 0.f;
        float vx1 = ((unsigned)ix1 < 96u) ? 1.f : 0.f;
        int r0 = min(max(iy0, 0), 95), r1 = min(max(iy1, 0), 95);
        int lb = min(max(ix0, 0), 94);
        // half-selects: which 16B cell (lb or lb+1) each x-corner lives in
        float h0 = (float)min(max(ix0 - lb, 0), 1);   // 1 only when ix0==95
        float h1 = (float)min(max(ix1 - lb, 0), 1);   // 0 only when ix0==-1
        float wx0 = (1.f - fx) * vx0, wx1 = fx * vx1;
        float xw0 = wx0 * (1.f - h0) + wx1 * (1.f - h1);
        float xw1 = wx0 * h0 + wx1 * h1;
        float rw0 = (1.f - fy) * vy0 * mm, rw1 = fy * vy1 * mm;
        cw[0] = rw0 * xw0; cw[1] = rw0 * xw1;
        cw[2] = rw1 * xw0; cw[3] = rw1 * xw1;
        const ushort* gp = xg1 + ((size_t)(b * 8 + g) * 9216) * 8;
        const ushort* p0 = gp + ((size_t)(r0 * 96 + lb)) * 8;
        const ushort* p1 = gp + ((size_t)(r1 * 96 + lb)) * 8;
        A[0] = *(const int4v*)p0;
        A[1] = *(const int4v*)(p0 + 8);
        A[2] = *(const int4v*)p1;
        A[3] = *(const int4v*)(p1 + 8);
    };

    // build a B-fragment from gathered corners
    auto LERP = [&](const int4v* A, const float* cw, half8* out) {
        union { int4v v; __half2 h2[4]; } a0, a1, b0, b1;
        a0.v = A[0]; a1.v = A[1]; b0.v = A[2]; b1.v = A[3];
        __half2 w0 = __float2half2_rn(cw[0]);
        __half2 w1 = __float2half2_rn(cw[1]);
        __half2 w2 = __float2half2_rn(cw[2]);
        __half2 w3 = __float2half2_rn(cw[3]);
        union { __half2 h2[4]; half8 v; } bu;
#pragma unroll
        for (int j = 0; j < 4; ++j) {
            __half2 t = __hmul2(a0.h2[j], w0);
            t = __hfma2(a1.h2[j], w1, t);
            t = __hfma2(b0.h2[j], w2, t);
            t = __hfma2(b1.h2[j], w3, t);
            bu.h2[j] = t;
        }
        *out = bu.v;
    };

    // consume step s: both groups share the 4 wdp af loads
    auto CONSUME2 = [&](int s, int par) {
        half8 bu0, bu1;
        LERP(Ab[par][0], cwb[par][0], &bu0);
        LERP(Ab[par][1], cwb[par][1], &bu1);
        int gkk = (kq * 6 + s) * 4 + l4;
#pragma unroll
        for (int mt = 0; mt < 4; ++mt) {
            half8 af = *(const half8*)(wdp +
                ((size_t)gkk * 64 + mt * 16 + l15) * 8);
            acc0[mt] = __builtin_amdgcn_mfma_f32_16x16x32_f16(
                af, bu0, acc0[mt], 0, 0, 0);
            acc1[mt] = __builtin_amdgcn_mfma_f32_16x16x32_f16(
                af, bu1, acc1[mt], 0, 0, 0);
        }
    };

    // s-major: om tiles (both groups) -> issue gathers -> consume s-1
#pragma unroll
    for (int s = 0; s < 6; ++s) {
        f32x4 aom0 = (f32x4){0.f, 0.f, 0.f, 0.f};
        f32x4 aom1 = (f32x4){0.f, 0.f, 0.f, 0.f};
#pragma unroll
        for (int kk = 0; kk < 9; ++kk) {
            int ky = kk / 3, kx = kk % 3;
#pragma unroll
            for (int cc = 0; cc < 2; ++cc) {
                int c8 = cc * 4 + l4;
                int P0 = ky * 34 + l15 + kx;
                int P1 = P0 + 16;
                bf16x8 bf0 = *(const bf16x8*)(s_x +
                    ((size_t)(P0 * 8 + (c8 ^ (P0 & 7)))) * 8);
                bf16x8 bf1 = *(const bf16x8*)(s_x +
                    ((size_t)(P1 * 8 + (c8 ^ (P1 & 7)))) * 8);
                bf16x8 af = *(const bf16x8*)(womp +
                    ((size_t)(((cc * 9 + kk) * 4 + l4) * 288)
                     + (kq * 6 + s) * 16 + l15) * 8);
                aom0 = __builtin_amdgcn_mfma_f32_16x16x32_bf16(
                    af, bf0, aom0, 0, 0, 0);
                aom1 = __builtin_amdgcn_mfma_f32_16x16x32_bf16(
                    af, bf1, aom1, 0, 0, 0);
            }
        }
        PREP(s, 0, aom0, Ab[s & 1][0], cwb[s & 1][0]);
        PREP(s, 1, aom1, Ab[s & 1][1], cwb[s & 1][1]);
        if (s >= 1) CONSUME2(s - 1, (s - 1) & 1);
    }
    CONSUME2(5, 1);

    // 3-way split-K reduce: kq=1,2 write, kq=0 adds + stores
    if (kq) {
#pragma unroll
        for (int mt = 0; mt < 4; ++mt)
#pragma unroll
            for (int r = 0; r < 4; ++r) {
                s_red[kq - 1][0][ln][mt * 4 + r] = acc0[mt][r];
                s_red[kq - 1][1][ln][mt * 4 + r] = acc1[mt][r];
            }
    }
    __syncthreads();
    if (!kq) {
#pragma unroll
        for (int gx = 0; gx < 2; ++gx) {
            size_t pb = (size_t)b * 9216 + px0 + gx * 16 + l15;
#pragma unroll
            for (int mt = 0; mt < 4; ++mt) {
                ushort hb[4];
#pragma unroll
                for (int r = 0; r < 4; ++r) {
                    int oc = mt * 16 + l4 * 4 + r;
                    float a = gx ? acc1[mt][r] : acc0[mt][r];
                    float v = a + s_red[0][gx][ln][mt * 4 + r]
                            + s_red[1][gx][ln][mt * 4 + r] + bd[oc];
                    hb[r] = f2bf(v);
                }
                uint2 pk;
                pk.x = (uint)hb[0] | ((uint)hb[1] << 16);
                pk.y = (uint)hb[2] | ((uint)hb[3] << 16);
                *(uint2*)(chl + pb * 128 + mt * 16 + l4 * 4) = pk;
            }
        }
    }
}

// ---------------------------------------------------------------------------
extern "C" void kernel_launch(void* const* d_in, const int* in_sizes, int n_in,
                              void* d_out, int out_size, void* d_ws, size_t ws_size,
                              hipStream_t stream) {
    const float* src0  = (const float*)d_in[0];
    const float* src1  = (const float*)d_in[1];
    const float* l_off = (const float*)d_in[2];
    const float* l_fea = (const float*)d_in[3];
    const float* w1 = (const float*)d_in[4];   const float* b1 = (const float*)d_in[5];
    const float* w2 = (const float*)d_in[6];   const float* b2 = (const float*)d_in[7];
    const float* w3 = (const float*)d_in[8];   const float* b3 = (const float*)d_in[9];
    const float* wom = (const float*)d_in[10]; const float* bom = (const float*)d_in[11];
    const float* wd = (const float*)d_in[12];  const float* bd = (const float*)d_in[13];
    const float* wf = (const float*)d_in[14];  const float* bf = (const float*)d_in[15];

    // workspace schedule (lifetimes annotated)
    char* W = (char*)d_ws;
    ushort* xin1 = (ushort*)(W + 0);          //  9,437,184 B  live to conv1
    ushort* xin2 = (ushort*)(W + 9437184);    //  9,437,184 B  dead after conv2
    ushort* xoff = (ushort*)(W + 9437184);    //  4,718,592 B  over xin2; live to dcn
    ushort* xin3 = (ushort*)(W + 18874368);   //  4,718,592 B  dead after conv3
    ushort* xin4 = (ushort*)(W + 44826624);   //  9,437,184 B  [b][px][128]
    ushort* xg1  = (ushort*)(W + 54263808);   //  4,718,592 B  [b][8][px][8] f16
    ushort* w1p  = (ushort*)(W + 58982400);   // 147,456 B
    ushort* w2p  = (ushort*)(W + 59129856);   // 147,456 B
    ushort* w3p  = (ushort*)(W + 59277312);   //  73,728 B
    ushort* womp = (ushort*)(W + 59351040);   // 331,776 B (288-wide permuted)
    ushort* wdp  = (ushort*)(W + 59682816);   //  73,728 B (f16)
    ushort* wfp  = (ushort*)(W + 59756544);   // 147,456 B
    float*  bpp  = (float*)(W + 59904000);    //   1,152 B permuted om bias
    float*  zgrd = (float*)(W + 59905152);    //      64 B zero guard

    float* out_off = (float*)d_out;
    float* out_fea = out_off + (size_t)4 * 64 * 9216;

    // fused packs + prepack (z=3)
    pack_combo_k<<<dim3(144, 4, 4), 256, 0, stream>>>(
        src0, src1, l_off, l_fea, w1, w2, w3, wom, wd, wf, bom,
        xin1, xin2, xin4, xg1, w1p, w2p, w3p, womp, wdp, wfp, bpp, zgrd);

    const ushort* zg = (const ushort*)zgrd;
    // conv1: xin1 -> xin2[0:64] (lrelu, ch-last)
    conv_mfma_k<128, 2, 2, true, false, true><<<1152, 256, 0, stream>>>(
        xin1, w1p, b1, nullptr, xin2, zg, 64, 64, 128, 0);
    // conv2: xin2 -> xin3 (lrelu, ch-last)
    conv_mfma_k<128, 2, 2, true, false, true><<<1152, 256, 0, stream>>>(
        xin2, w2p, b2, nullptr, xin3, zg, 64, 64, 64, 0);
    // conv3: xin3 -> out_off (fp32 NCHW) + xoff (ch-last)
    conv_mfma_k<64, 2, 2, true, true, true><<<1152, 256, 0, stream>>>(
        xin3, w3p, b3, out_off, xoff, zg, 64, 64, 64, 0);
    // fused om-conv + DCN -> xin4[0:64]  (32-px band, weight-fragment reuse)
    dcn_fused_k<<<1152, 192, 0, stream>>>(xoff, xg1, womp, bpp, wdp, bd,
                                          xin4, zg);
    // fea conv: xin4 -> out_fea (fp32 NCHW, lrelu)
    conv_mfma_k<128, 2, 2, true, true, false><<<1152, 256, 0, stream>>>(
        xin4, wfp, bf, out_fea, nullptr, zg, 64, 64, 0, 0);
}

// Round 15
// 125.841 us; speedup vs baseline: 1.6311x; 1.6311x over previous
//
#include <hip/hip_runtime.h>
#include <hip/hip_fp16.h>
#include <math.h>

typedef __attribute__((ext_vector_type(8))) short bf16x8;
typedef __attribute__((ext_vector_type(8))) _Float16 half8;
typedef __attribute__((ext_vector_type(4))) float f32x4;
typedef __attribute__((ext_vector_type(4))) int int4v;

#define GL_LDS16(g, l) __builtin_amdgcn_global_load_lds( \
    (const __attribute__((address_space(1))) void*)(g), \
    (__attribute__((address_space(3))) void*)(l), 16, 0, 0)

__device__ __forceinline__ ushort f2bf(float f) {
    union { float f; unsigned u; } v; v.f = f;
    unsigned r = (v.u + 0x7fffu + ((v.u >> 16) & 1u)) >> 16;
    return (ushort)r;
}
__device__ __forceinline__ float bf2f(ushort h) {
    union { unsigned u; float f; } v; v.u = ((unsigned)h) << 16;
    return v.f;
}

// ---------------------------------------------------------------------------
// Weight prepack helper: w[oc][cin][3][3] -> wp[cc][kk][kg][CoutP][8]
__device__ __forceinline__ void prep_one(const float* __restrict__ w,
        ushort* __restrict__ wp, int u, int Cin, int CoutR, int CoutP) {
    int oc = u % CoutP; int t = u / CoutP;
    int kg = t & 3; t >>= 2;
    int kk = t % 9; int cc = t / 9;
    alignas(16) ushort tmp[8];
    for (int j = 0; j < 8; ++j) {
        int c = cc * 32 + kg * 8 + j;
        float v = (oc < CoutR) ? w[((size_t)oc * Cin + c) * 9 + kk] : 0.f;
        tmp[j] = f2bf(v);
    }
    *(int4v*)(wp + (size_t)u * 8) = *(int4v*)tmp;
}

// ---------------------------------------------------------------------------
// Fused packs + prepack:
//  z=0: pack concat(src0,src1)->xin1[px][128] (bf16) AND xg1[b][g][px][8] (f16)
//  z=1: up2(l_off)*2 -> xin2[px][64:128]; z=2: up2(l_fea) -> xin4[px][64:128]
//  z=3: all weight prepacks (wd -> f16) + om bias permute + zero guard
__global__ __launch_bounds__(256) void pack_combo_k(
        const float* __restrict__ s0, const float* __restrict__ s1,
        const float* __restrict__ lo, const float* __restrict__ lf,
        const float* __restrict__ w1, const float* __restrict__ w2,
        const float* __restrict__ w3, const float* __restrict__ wom,
        const float* __restrict__ wd, const float* __restrict__ wf,
        const float* __restrict__ bom,
        ushort* __restrict__ xin1, ushort* __restrict__ xin2,
        ushort* __restrict__ xin4, ushort* __restrict__ xg1,
        ushort* __restrict__ w1p, ushort* __restrict__ w2p,
        ushort* __restrict__ w3p, ushort* __restrict__ womp,
        ushort* __restrict__ wdp, ushort* __restrict__ wfp,
        float* __restrict__ bpp, float* __restrict__ zg) {
    int b = blockIdx.y;
    int z = blockIdx.z;
    int px = blockIdx.x * 64 + (threadIdx.x & 63);
    int u = threadIdx.x >> 6;
    if (z == 0) {
        for (int half = 0; half < 2; ++half) {
            int cg = u + half * 4;
            float vals[16];
            alignas(16) ushort tmp[16];
            for (int i = 0; i < 16; ++i) {
                int c = cg * 16 + i;
                float v = (c < 64) ? s0[((size_t)(b * 64 + c)) * 9216 + px]
                                   : s1[((size_t)(b * 64 + c - 64)) * 9216 + px];
                vals[i] = v;
                tmp[i] = f2bf(v);
            }
            ushort* dst = xin1 + ((size_t)(b * 9216) + px) * 128 + cg * 16;
            *(int4v*)dst = *(int4v*)&tmp[0];
            *(int4v*)(dst + 8) = *(int4v*)&tmp[8];
            if (half == 0) {
                // gather copy in f16: groups g = cg*2, cg*2+1
                alignas(16) __half th[16];
                for (int i = 0; i < 16; ++i) th[i] = __float2half(vals[i]);
                ushort* gdst = xg1 + (((size_t)(b * 8 + cg * 2) * 9216) + px) * 8;
                *(int4v*)gdst = *(int4v*)&th[0];
                *(int4v*)(gdst + 9216 * 8) = *(int4v*)&th[8];
            }
        }
    } else if (z < 3) {
        const float* in = (z == 1) ? lo : lf;
        float scale = (z == 1) ? 2.0f : 1.0f;
        ushort* xo = (z == 1) ? xin2 : xin4;
        int y = px / 96, x = px % 96;
        float sy = fmaxf(y * 0.5f - 0.25f, 0.f);
        float sx = fmaxf(x * 0.5f - 0.25f, 0.f);
        int y0 = (int)sy, x0 = (int)sx;
        float ty = sy - (float)y0, tx = sx - (float)x0;
        int y1 = min(y0 + 1, 47), x1 = min(x0 + 1, 47);
        alignas(16) ushort tmp[16];
        for (int i = 0; i < 16; ++i) {
            int c = u * 16 + i;
            const float* p = in + ((size_t)(b * 64 + c)) * 2304;
            float v00 = p[y0 * 48 + x0], v01 = p[y0 * 48 + x1];
            float v10 = p[y1 * 48 + x0], v11 = p[y1 * 48 + x1];
            float v = (v00 * (1.f - tx) + v01 * tx) * (1.f - ty)
                    + (v10 * (1.f - tx) + v11 * tx) * ty;
            tmp[i] = f2bf(v * scale);
        }
        ushort* dst = xo + ((size_t)(b * 9216) + px) * 128 + 64 + u * 16;
        *(int4v*)dst = *(int4v*)&tmp[0];
        *(int4v*)(dst + 8) = *(int4v*)&tmp[8];
    } else {
        // prepack: 57904 units over 576 blocks
        int uu = (blockIdx.x + 144 * blockIdx.y) * 256 + threadIdx.x;
        if (uu < 9216) prep_one(w1, w1p, uu, 128, 64, 64);
        else if (uu < 18432) prep_one(w2, w2p, uu - 9216, 128, 64, 64);
        else if (uu < 23040) prep_one(w3, w3p, uu - 18432, 64, 64, 64);
        else if (uu < 43776) {
            // om conv, permuted: CoutP=288, oc p = gkk*4 + t3 (t3==3 -> pad)
            int v = uu - 23040;               // units = 2*9*4*288 = 20736
            int ocp = v % 288; int t = v / 288;
            int kg = t & 3; t >>= 2;
            int kk = t % 9; int cc = t / 9;
            int t3 = ocp & 3, gkkp = ocp >> 2;
            alignas(16) ushort tmp[8];
            for (int j = 0; j < 8; ++j) {
                int c = cc * 32 + kg * 8 + j;
                float vv = (t3 < 3)
                    ? wom[((size_t)(t3 * 72 + gkkp) * 64 + c) * 9 + kk] : 0.f;
                tmp[j] = f2bf(vv);
            }
            *(int4v*)(womp + (size_t)v * 8) = *(int4v*)tmp;
        } else if (uu < 48384) {
            int v = uu - 43776;               // wd -> f16 [gkk*64 + oc][8]
            int oc = v & 63; int gkk = v >> 6;
            int g = gkk / 9, kk = gkk % 9;
            alignas(16) __half tmp[8];
            for (int j = 0; j < 8; ++j)
                tmp[j] = __float2half(wd[((size_t)oc * 64 + g * 8 + j) * 9 + kk]);
            *(int4v*)(wdp + (size_t)v * 8) = *(int4v*)tmp;
        } else if (uu < 57600) prep_one(wf, wfp, uu - 48384, 128, 64, 64);
        else if (uu < 57888) {
            int ocp = uu - 57600; int t3 = ocp & 3, gkkp = ocp >> 2;
            bpp[ocp] = (t3 < 3) ? bom[t3 * 72 + gkkp] : 0.f;
        } else if (uu < 57904) zg[uu - 57888] = 0.f;  // 64-B zero guard
    }
}

// ---------------------------------------------------------------------------
// MFMA 3x3 conv: per-wave MT*16 oc x 16 px, block = 8x8 px tile.
// Activation staged in 64-channel slices via global_load_lds; zero-guard for
// pad/OOB. CIN=64: single stage (one barrier). CIN=128: 2 slices dbuf.
// A-fragments read directly from global prepacked weights (L1-hot).
template<int CIN, int MT, int NZ, bool LRELU, bool ST_F32, bool ST_CHL>
__global__ __launch_bounds__(256, 4) void conv_mfma_k(
        const ushort* __restrict__ xin,      // [b][9216][CIN] bf16
        const ushort* __restrict__ wp,       // [CIN/32][9][4][CoutP][8]
        const float* __restrict__ bias,
        float* __restrict__ outf,            // NCHW fp32
        ushort* __restrict__ chl,            // ch-last bf16
        const ushort* __restrict__ zg,       // 64-B zero guard
        int CoutR, int CoutP, int ochs, int ocoff) {
    constexpr int SL = CIN / 64;
    constexpr int OCN = MT * 16;
    __shared__ ushort s_act[SL][7200];        // [buf][100 rows x 72u] 14.4 KB each

    int tid = threadIdx.x;
    int wv = tid >> 6, ln = tid & 63;
    int l15 = ln & 15, l4 = ln >> 4;

    constexpr int TOTAL = 144 * 4 * NZ;
    constexpr int CHUNK = TOTAL / 8;
    int bid = blockIdx.x;
    int nid = (bid & 7) * CHUNK + (bid >> 3);
    int zc = nid % NZ; int r1 = nid / NZ;
    int tile = r1 % 144; int b = r1 / 144;    // b-major banding
    int bx = (tile % 12) * 8, by = (tile / 12) * 8;
    int oc0 = zc * OCN;

    int px_l = wv * 16 + l15;                 // px in 8x8 tile
    int py = px_l >> 3, pxx = px_l & 7;
    int b_base = (py * 10 + pxx) * 72 + l4 * 8;

    const ushort* wlane = wp + ((size_t)l4 * CoutP + oc0 + l15) * 8;

    f32x4 acc[MT];
#pragma unroll
    for (int mt = 0; mt < MT; ++mt) acc[mt] = (f32x4){0.f, 0.f, 0.f, 0.f};

    auto STAGE = [&](int sl, int buf) {
        for (int i = tid; i < 900; i += 256) {
            int p = i / 9, q = i - p * 9;     // q==8 -> pad slot
            int gy = by + (p / 10) - 1, gx = bx + (p % 10) - 1;
            const ushort* src = zg;
            if (q < 8 && (unsigned)gy < 96u && (unsigned)gx < 96u)
                src = xin + ((size_t)(b * 9216 + gy * 96 + gx) * CIN
                             + sl * 64 + q * 8);
            GL_LDS16(src, s_act[buf] + (size_t)i * 8);
        }
    };

    STAGE(0, 0);
    __syncthreads();
#pragma unroll
    for (int sl = 0; sl < SL; ++sl) {
        if (sl + 1 < SL) STAGE(sl + 1, (sl + 1) & 1);
#pragma unroll
        for (int cc2 = 0; cc2 < 2; ++cc2) {
#pragma unroll
            for (int kk = 0; kk < 9; ++kk) {
                bf16x8 bfrag = *(const bf16x8*)(s_act[sl & (SL - 1)] + b_base +
                                   ((kk / 3) * 10 + (kk % 3)) * 72 + cc2 * 32);
#pragma unroll
                for (int mt = 0; mt < MT; ++mt) {
                    bf16x8 af = *(const bf16x8*)(wlane +
                        ((size_t)((sl * 2 + cc2) * 36 + kk * 4) * CoutP + mt * 16) * 8);
                    acc[mt] = __builtin_amdgcn_mfma_f32_16x16x32_bf16(
                        af, bfrag, acc[mt], 0, 0, 0);
                }
            }
        }
        if (sl + 1 < SL) __syncthreads();
    }

    int gy = by + py, gx = bx + pxx;
    size_t pxg = (size_t)b * 9216 + gy * 96 + gx;
#pragma unroll
    for (int mt = 0; mt < MT; ++mt) {
        int ocb = oc0 + mt * 16 + l4 * 4;
        ushort hb[4];
#pragma unroll
        for (int r = 0; r < 4; ++r) {
            int oc = ocb + r;
            float v = acc[mt][r] + ((oc < CoutR) ? bias[oc] : 0.f);
            if (LRELU) v = (v >= 0.f) ? v : 0.1f * v;
            hb[r] = f2bf(v);
            if (ST_F32 && oc < CoutR)
                outf[((size_t)b * CoutR + oc) * 9216 + gy * 96 + gx] = v;
        }
        if (ST_CHL && ocb < CoutR) {
            uint2 pk;
            pk.x = (uint)hb[0] | ((uint)hb[1] << 16);
            pk.y = (uint)hb[2] | ((uint)hb[3] << 16);
            *(uint2*)(chl + pxg * ochs + ocoff + ocb) = pk;
        }
    }
}

// ---------------------------------------------------------------------------
// Fused om-conv + DCNv2, 3-way split-K, 32-px band, LDS-landed gathers.
// Weight A-fragments (womp, wdp) each feed BOTH px-groups (2x traffic reuse).
// Gathers use global_load_lds with per-lane global source -> zero VGPR
// in-flight cost (r14's spill fix). Step order: om-MFMA(s) -> consume(s-1)
// [vmcnt(0) + zone ds_read + lerp + 8 PV MFMA] -> PREP(s) issues 8 gathers.
// Gather latency covered by step s+1's 36-MFMA om phase. grid = 1152 x 192.
__global__ __launch_bounds__(192, 2) void dcn_fused_k(
        const ushort* __restrict__ xoff,     // [b][px][64] ch-last bf16
        const ushort* __restrict__ xg1,      // [b][8][9216][8] f16
        const ushort* __restrict__ womp,     // [cc][kk][4][288][8] bf16
        const float* __restrict__ bpp,       // permuted om bias [288]
        const ushort* __restrict__ wdp,      // f16 [gkk*64+oc][8]
        const float* __restrict__ bd, ushort* __restrict__ chl,
        const ushort* __restrict__ zg) {
    __shared__ ushort s_x[816 * 8];           // halo band: 13,056 B
    __shared__ ushort s_zone[3 * 2 * 4 * 64 * 8];  // gather zone: 24,576 B
    __shared__ float s_red[2][2][64][17];     // 34,816 B -> 72.4 KB total
    int tid = threadIdx.x;
    int kq = tid >> 6, ln = tid & 63;
    int l15 = ln & 15, l4 = ln >> 4;
    int bid = blockIdx.x;                     // 0..1151
    int nid = (bid & 7) * 144 + (bid >> 3);   // XCD-chunked swizzle
    int pxb = nid % 288; int b = nid / 288;   // b-major banding
    int px0 = pxb * 32;
    int y = px0 / 96, x0 = px0 % 96;          // x0 in {0,32,64}

    // ---- stage xoff halo band (rows y-1..y+1, cols x0-1..x0+32) ----
    for (int i = tid; i < 816; i += 192) {
        int P = i >> 3, s8 = i & 7;
        int q = s8 ^ (P & 7);                 // inverse-swizzled source chunk
        int ry = y - 1 + P / 34, rx = x0 - 1 + P % 34;
        const ushort* src = zg;
        if ((unsigned)ry < 96u && (unsigned)rx < 96u)
            src = xoff + (((size_t)b * 9216 + ry * 96 + rx) * 64 + q * 8);
        GL_LDS16(src, s_x + (size_t)i * 8);
    }
    __syncthreads();

    f32x4 acc0[4], acc1[4];
#pragma unroll
    for (int mt = 0; mt < 4; ++mt) {
        acc0[mt] = (f32x4){0.f, 0.f, 0.f, 0.f};
        acc1[mt] = (f32x4){0.f, 0.f, 0.f, 0.f};
    }

    float cwb[2][4];                          // lerp weights, 1 step live

    // address calc + ISSUE 4 gathers-to-LDS for (step s, group gx)
    auto PREP = [&](int s, int gx, const f32x4& aom) {
        int st = kq * 6 + s;
        int gkk = st * 4 + l4;
        int g = gkk / 9, kk = gkk - g * 9;
        int bofs = st * 16 + l4 * 4;
        int xx = x0 + gx * 16 + l15;
        float oy = aom[0] + bpp[bofs];
        float ox = aom[1] + bpp[bofs + 1];
        float mm = 1.f / (1.f + __expf(-(aom[2] + bpp[bofs + 2])));
        float py = oy + (float)(y + kk / 3 - 1);
        float pxf = ox + (float)(xx + kk % 3 - 1);
        float yf = floorf(py), xf = floorf(pxf);
        float fy = py - yf, fx = pxf - xf;
        int iy0 = (int)yf, ix0 = (int)xf;
        int iy1 = iy0 + 1, ix1 = ix0 + 1;
        float vy0 = ((unsigned)iy0 < 96u) ? 1.f : 0.f;
        float vy1 = ((unsigned)iy1 < 96u) ? 1.f : 0.f;
        float vx0 = ((unsigned)ix0 < 96u) ? 1.f : 0.f;
        float vx1 = ((unsigned)ix1 < 96u) ? 1.f : 0.f;
        int r0 = min(max(iy0, 0), 95), r1 = min(max(iy1, 0), 95);
        int lb = min(max(ix0, 0), 94);
        // half-selects: which 16B cell (lb or lb+1) each x-corner lives in
        float h0 = (float)min(max(ix0 - lb, 0), 1);   // 1 only when ix0==95
        float h1 = (float)min(max(ix1 - lb, 0), 1);   // 0 only when ix0==-1
        float wx0 = (1.f - fx) * vx0, wx1 = fx * vx1;
        float xw0 = wx0 * (1.f - h0) + wx1 * (1.f - h1);
        float xw1 = wx0 * h0 + wx1 * h1;
        float rw0 = (1.f - fy) * vy0 * mm, rw1 = fy * vy1 * mm;
        cwb[gx][0] = rw0 * xw0; cwb[gx][1] = rw0 * xw1;
        cwb[gx][2] = rw1 * xw0; cwb[gx][3] = rw1 * xw1;
        const ushort* gp = xg1 + ((size_t)(b * 8 + g) * 9216) * 8;
        const ushort* p0 = gp + ((size_t)(r0 * 96 + lb)) * 8;
        const ushort* p1 = gp + ((size_t)(r1 * 96 + lb)) * 8;
        ushort* zb = s_zone + ((size_t)((kq * 2 + gx) * 4) * 64 + ln) * 8;
        GL_LDS16(p0,     zb);
        GL_LDS16(p0 + 8, zb + 64 * 8);
        GL_LDS16(p1,     zb + 128 * 8);
        GL_LDS16(p1 + 8, zb + 192 * 8);
    };

    // consume step s: drain gathers, lerp both groups, 8 MFMA on 4 shared af
    auto CONSUME2 = [&](int s) {
        asm volatile("s_waitcnt vmcnt(0)" ::: "memory");
        __builtin_amdgcn_sched_barrier(0);
        half8 bu[2];
#pragma unroll
        for (int gx = 0; gx < 2; ++gx) {
            const ushort* zb = s_zone + ((size_t)((kq * 2 + gx) * 4) * 64 + ln) * 8;
            union { int4v v; __half2 h2[4]; } a0, a1, b0c, b1c;
            a0.v  = *(const int4v*)zb;
            a1.v  = *(const int4v*)(zb + 64 * 8);
            b0c.v = *(const int4v*)(zb + 128 * 8);
            b1c.v = *(const int4v*)(zb + 192 * 8);
            __half2 w0 = __float2half2_rn(cwb[gx][0]);
            __half2 w1 = __float2half2_rn(cwb[gx][1]);
            __half2 w2 = __float2half2_rn(cwb[gx][2]);
            __half2 w3 = __float2half2_rn(cwb[gx][3]);
            union { __half2 h2[4]; half8 v; } buv;
#pragma unroll
            for (int j = 0; j < 4; ++j) {
                __half2 t = __hmul2(a0.h2[j], w0);
                t = __hfma2(a1.h2[j], w1, t);
                t = __hfma2(b0c.h2[j], w2, t);
                t = __hfma2(b1c.h2[j], w3, t);
                buv.h2[j] = t;
            }
            bu[gx] = buv.v;
        }
        int gkk = (kq * 6 + s) * 4 + l4;
#pragma unroll
        for (int mt = 0; mt < 4; ++mt) {
            half8 af = *(const half8*)(wdp +
                ((size_t)gkk * 64 + mt * 16 + l15) * 8);
            acc0[mt] = __builtin_amdgcn_mfma_f32_16x16x32_f16(
                af, bu[0], acc0[mt], 0, 0, 0);
            acc1[mt] = __builtin_amdgcn_mfma_f32_16x16x32_f16(
                af, bu[1], acc1[mt], 0, 0, 0);
        }
    };

    // s-major: om tiles (both groups, shared af) -> consume s-1 -> issue s
#pragma unroll
    for (int s = 0; s < 7; ++s) {
        f32x4 aom0 = (f32x4){0.f, 0.f, 0.f, 0.f};
        f32x4 aom1 = (f32x4){0.f, 0.f, 0.f, 0.f};
        if (s < 6) {
#pragma unroll
            for (int kk = 0; kk < 9; ++kk) {
                int ky = kk / 3, kx = kk % 3;
#pragma unroll
                for (int cc = 0; cc < 2; ++cc) {
                    int c8 = cc * 4 + l4;
                    int P0 = ky * 34 + l15 + kx;
                    int P1 = P0 + 16;
                    bf16x8 bf0 = *(const bf16x8*)(s_x +
                        ((size_t)(P0 * 8 + (c8 ^ (P0 & 7)))) * 8);
                    bf16x8 bf1 = *(const bf16x8*)(s_x +
                        ((size_t)(P1 * 8 + (c8 ^ (P1 & 7)))) * 8);
                    bf16x8 af = *(const bf16x8*)(womp +
                        ((size_t)(((cc * 9 + kk) * 4 + l4) * 288)
                         + (kq * 6 + s) * 16 + l15) * 8);
                    aom0 = __builtin_amdgcn_mfma_f32_16x16x32_bf16(
                        af, bf0, aom0, 0, 0, 0);
                    aom1 = __builtin_amdgcn_mfma_f32_16x16x32_bf16(
                        af, bf1, aom1, 0, 0, 0);
                }
            }
        }
        if (s >= 1) CONSUME2(s - 1);
        if (s < 6) {
            PREP(s, 0, aom0);
            PREP(s, 1, aom1);
        }
    }

    // 3-way split-K reduce: kq=1,2 write, kq=0 adds + stores
    if (kq) {
#pragma unroll
        for (int mt = 0; mt < 4; ++mt)
#pragma unroll
            for (int r = 0; r < 4; ++r) {
                s_red[kq - 1][0][ln][mt * 4 + r] = acc0[mt][r];
                s_red[kq - 1][1][ln][mt * 4 + r] = acc1[mt][r];
            }
    }
    __syncthreads();
    if (!kq) {
#pragma unroll
        for (int gx = 0; gx < 2; ++gx) {
            size_t pb = (size_t)b * 9216 + px0 + gx * 16 + l15;
#pragma unroll
            for (int mt = 0; mt < 4; ++mt) {
                ushort hb[4];
#pragma unroll
                for (int r = 0; r < 4; ++r) {
                    int oc = mt * 16 + l4 * 4 + r;
                    float a = gx ? acc1[mt][r] : acc0[mt][r];
                    float v = a + s_red[0][gx][ln][mt * 4 + r]
                            + s_red[1][gx][ln][mt * 4 + r] + bd[oc];
                    hb[r] = f2bf(v);
                }
                uint2 pk;
                pk.x = (uint)hb[0] | ((uint)hb[1] << 16);
                pk.y = (uint)hb[2] | ((uint)hb[3] << 16);
                *(uint2*)(chl + pb * 128 + mt * 16 + l4 * 4) = pk;
            }
        }
    }
}

// ---------------------------------------------------------------------------
extern "C" void kernel_launch(void* const* d_in, const int* in_sizes, int n_in,
                              void* d_out, int out_size, void* d_ws, size_t ws_size,
                              hipStream_t stream) {
    const float* src0  = (const float*)d_in[0];
    const float* src1  = (const float*)d_in[1];
    const float* l_off = (const float*)d_in[2];
    const float* l_fea = (const float*)d_in[3];
    const float* w1 = (const float*)d_in[4];   const float* b1 = (const float*)d_in[5];
    const float* w2 = (const float*)d_in[6];   const float* b2 = (const float*)d_in[7];
    const float* w3 = (const float*)d_in[8];   const float* b3 = (const float*)d_in[9];
    const float* wom = (const float*)d_in[10]; const float* bom = (const float*)d_in[11];
    const float* wd = (const float*)d_in[12];  const float* bd = (const float*)d_in[13];
    const float* wf = (const float*)d_in[14];  const float* bf = (const float*)d_in[15];

    // workspace schedule (lifetimes annotated)
    char* W = (char*)d_ws;
    ushort* xin1 = (ushort*)(W + 0);          //  9,437,184 B  live to conv1
    ushort* xin2 = (ushort*)(W + 9437184);    //  9,437,184 B  dead after conv2
    ushort* xoff = (ushort*)(W + 9437184);    //  4,718,592 B  over xin2; live to dcn
    ushort* xin3 = (ushort*)(W + 18874368);   //  4,718,592 B  dead after conv3
    ushort* xin4 = (ushort*)(W + 44826624);   //  9,437,184 B  [b][px][128]
    ushort* xg1  = (ushort*)(W + 54263808);   //  4,718,592 B  [b][8][px][8] f16
    ushort* w1p  = (ushort*)(W + 58982400);   // 147,456 B
    ushort* w2p  = (ushort*)(W + 59129856);   // 147,456 B
    ushort* w3p  = (ushort*)(W + 59277312);   //  73,728 B
    ushort* womp = (ushort*)(W + 59351040);   // 331,776 B (288-wide permuted)
    ushort* wdp  = (ushort*)(W + 59682816);   //  73,728 B (f16)
    ushort* wfp  = (ushort*)(W + 59756544);   // 147,456 B
    float*  bpp  = (float*)(W + 59904000);    //   1,152 B permuted om bias
    float*  zgrd = (float*)(W + 59905152);    //      64 B zero guard

    float* out_off = (float*)d_out;
    float* out_fea = out_off + (size_t)4 * 64 * 9216;

    // fused packs + prepack (z=3)
    pack_combo_k<<<dim3(144, 4, 4), 256, 0, stream>>>(
        src0, src1, l_off, l_fea, w1, w2, w3, wom, wd, wf, bom,
        xin1, xin2, xin4, xg1, w1p, w2p, w3p, womp, wdp, wfp, bpp, zgrd);

    const ushort* zg = (const ushort*)zgrd;
    // conv1: xin1 -> xin2[0:64] (lrelu, ch-last)
    conv_mfma_k<128, 2, 2, true, false, true><<<1152, 256, 0, stream>>>(
        xin1, w1p, b1, nullptr, xin2, zg, 64, 64, 128, 0);
    // conv2: xin2 -> xin3 (lrelu, ch-last)
    conv_mfma_k<128, 2, 2, true, false, true><<<1152, 256, 0, stream>>>(
        xin2, w2p, b2, nullptr, xin3, zg, 64, 64, 64, 0);
    // conv3: xin3 -> out_off (fp32 NCHW) + xoff (ch-last)
    conv_mfma_k<64, 2, 2, true, true, true><<<1152, 256, 0, stream>>>(
        xin3, w3p, b3, out_off, xoff, zg, 64, 64, 64, 0);
    // fused om-conv + DCN -> xin4[0:64]  (32-px band, LDS-landed gathers)
    dcn_fused_k<<<1152, 192, 0, stream>>>(xoff, xg1, womp, bpp, wdp, bd,
                                          xin4, zg);
    // fea conv: xin4 -> out_fea (fp32 NCHW, lrelu)
    conv_mfma_k<128, 2, 2, true, true, false><<<1152, 256, 0, stream>>>(
        xin4, wfp, bf, out_fea, nullptr, zg, 64, 64, 0, 0);
}

// Round 16
// 123.442 us; speedup vs baseline: 1.6628x; 1.0194x over previous
//
#include <hip/hip_runtime.h>
#include <hip/hip_fp16.h>
#include <math.h>

typedef __attribute__((ext_vector_type(8))) short bf16x8;
typedef __attribute__((ext_vector_type(8))) _Float16 half8;
typedef __attribute__((ext_vector_type(4))) float f32x4;
typedef __attribute__((ext_vector_type(4))) int int4v;

#define GL_LDS16(g, l) __builtin_amdgcn_global_load_lds( \
    (const __attribute__((address_space(1))) void*)(g), \
    (__attribute__((address_space(3))) void*)(l), 16, 0, 0)

__device__ __forceinline__ ushort f2bf(float f) {
    union { float f; unsigned u; } v; v.f = f;
    unsigned r = (v.u + 0x7fffu + ((v.u >> 16) & 1u)) >> 16;
    return (ushort)r;
}
__device__ __forceinline__ float bf2f(ushort h) {
    union { unsigned u; float f; } v; v.u = ((unsigned)h) << 16;
    return v.f;
}

// ---------------------------------------------------------------------------
// Weight prepack helper: w[oc][cin][3][3] -> wp[cc][kk][kg][CoutP][8]
__device__ __forceinline__ void prep_one(const float* __restrict__ w,
        ushort* __restrict__ wp, int u, int Cin, int CoutR, int CoutP) {
    int oc = u % CoutP; int t = u / CoutP;
    int kg = t & 3; t >>= 2;
    int kk = t % 9; int cc = t / 9;
    alignas(16) ushort tmp[8];
    for (int j = 0; j < 8; ++j) {
        int c = cc * 32 + kg * 8 + j;
        float v = (oc < CoutR) ? w[((size_t)oc * Cin + c) * 9 + kk] : 0.f;
        tmp[j] = f2bf(v);
    }
    *(int4v*)(wp + (size_t)u * 8) = *(int4v*)tmp;
}

// ---------------------------------------------------------------------------
// Fused packs + prepack:
//  z=0: pack concat(src0,src1)->xin1[px][128] (bf16) AND xg1[b][g][px][8] (f16)
//  z=1: up2(l_off)*2 -> xin2[px][64:128]; z=2: up2(l_fea) -> xin4[px][64:128]
//  z=3: all weight prepacks (wd -> f16) + om bias permute + zero guard
__global__ __launch_bounds__(256) void pack_combo_k(
        const float* __restrict__ s0, const float* __restrict__ s1,
        const float* __restrict__ lo, const float* __restrict__ lf,
        const float* __restrict__ w1, const float* __restrict__ w2,
        const float* __restrict__ w3, const float* __restrict__ wom,
        const float* __restrict__ wd, const float* __restrict__ wf,
        const float* __restrict__ bom,
        ushort* __restrict__ xin1, ushort* __restrict__ xin2,
        ushort* __restrict__ xin4, ushort* __restrict__ xg1,
        ushort* __restrict__ w1p, ushort* __restrict__ w2p,
        ushort* __restrict__ w3p, ushort* __restrict__ womp,
        ushort* __restrict__ wdp, ushort* __restrict__ wfp,
        float* __restrict__ bpp, float* __restrict__ zg) {
    int b = blockIdx.y;
    int z = blockIdx.z;
    int px = blockIdx.x * 64 + (threadIdx.x & 63);
    int u = threadIdx.x >> 6;
    if (z == 0) {
        for (int half = 0; half < 2; ++half) {
            int cg = u + half * 4;
            float vals[16];
            alignas(16) ushort tmp[16];
            for (int i = 0; i < 16; ++i) {
                int c = cg * 16 + i;
                float v = (c < 64) ? s0[((size_t)(b * 64 + c)) * 9216 + px]
                                   : s1[((size_t)(b * 64 + c - 64)) * 9216 + px];
                vals[i] = v;
                tmp[i] = f2bf(v);
            }
            ushort* dst = xin1 + ((size_t)(b * 9216) + px) * 128 + cg * 16;
            *(int4v*)dst = *(int4v*)&tmp[0];
            *(int4v*)(dst + 8) = *(int4v*)&tmp[8];
            if (half == 0) {
                // gather copy in f16: groups g = cg*2, cg*2+1
                alignas(16) __half th[16];
                for (int i = 0; i < 16; ++i) th[i] = __float2half(vals[i]);
                ushort* gdst = xg1 + (((size_t)(b * 8 + cg * 2) * 9216) + px) * 8;
                *(int4v*)gdst = *(int4v*)&th[0];
                *(int4v*)(gdst + 9216 * 8) = *(int4v*)&th[8];
            }
        }
    } else if (z < 3) {
        const float* in = (z == 1) ? lo : lf;
        float scale = (z == 1) ? 2.0f : 1.0f;
        ushort* xo = (z == 1) ? xin2 : xin4;
        int y = px / 96, x = px % 96;
        float sy = fmaxf(y * 0.5f - 0.25f, 0.f);
        float sx = fmaxf(x * 0.5f - 0.25f, 0.f);
        int y0 = (int)sy, x0 = (int)sx;
        float ty = sy - (float)y0, tx = sx - (float)x0;
        int y1 = min(y0 + 1, 47), x1 = min(x0 + 1, 47);
        alignas(16) ushort tmp[16];
        for (int i = 0; i < 16; ++i) {
            int c = u * 16 + i;
            const float* p = in + ((size_t)(b * 64 + c)) * 2304;
            float v00 = p[y0 * 48 + x0], v01 = p[y0 * 48 + x1];
            float v10 = p[y1 * 48 + x0], v11 = p[y1 * 48 + x1];
            float v = (v00 * (1.f - tx) + v01 * tx) * (1.f - ty)
                    + (v10 * (1.f - tx) + v11 * tx) * ty;
            tmp[i] = f2bf(v * scale);
        }
        ushort* dst = xo + ((size_t)(b * 9216) + px) * 128 + 64 + u * 16;
        *(int4v*)dst = *(int4v*)&tmp[0];
        *(int4v*)(dst + 8) = *(int4v*)&tmp[8];
    } else {
        // prepack: 57904 units over 576 blocks
        int uu = (blockIdx.x + 144 * blockIdx.y) * 256 + threadIdx.x;
        if (uu < 9216) prep_one(w1, w1p, uu, 128, 64, 64);
        else if (uu < 18432) prep_one(w2, w2p, uu - 9216, 128, 64, 64);
        else if (uu < 23040) prep_one(w3, w3p, uu - 18432, 64, 64, 64);
        else if (uu < 43776) {
            // om conv, permuted: CoutP=288, oc p = gkk*4 + t3 (t3==3 -> pad)
            int v = uu - 23040;               // units = 2*9*4*288 = 20736
            int ocp = v % 288; int t = v / 288;
            int kg = t & 3; t >>= 2;
            int kk = t % 9; int cc = t / 9;
            int t3 = ocp & 3, gkkp = ocp >> 2;
            alignas(16) ushort tmp[8];
            for (int j = 0; j < 8; ++j) {
                int c = cc * 32 + kg * 8 + j;
                float vv = (t3 < 3)
                    ? wom[((size_t)(t3 * 72 + gkkp) * 64 + c) * 9 + kk] : 0.f;
                tmp[j] = f2bf(vv);
            }
            *(int4v*)(womp + (size_t)v * 8) = *(int4v*)tmp;
        } else if (uu < 48384) {
            int v = uu - 43776;               // wd -> f16 [gkk*64 + oc][8]
            int oc = v & 63; int gkk = v >> 6;
            int g = gkk / 9, kk = gkk % 9;
            alignas(16) __half tmp[8];
            for (int j = 0; j < 8; ++j)
                tmp[j] = __float2half(wd[((size_t)oc * 64 + g * 8 + j) * 9 + kk]);
            *(int4v*)(wdp + (size_t)v * 8) = *(int4v*)tmp;
        } else if (uu < 57600) prep_one(wf, wfp, uu - 48384, 128, 64, 64);
        else if (uu < 57888) {
            int ocp = uu - 57600; int t3 = ocp & 3, gkkp = ocp >> 2;
            bpp[ocp] = (t3 < 3) ? bom[t3 * 72 + gkkp] : 0.f;
        } else if (uu < 57904) zg[uu - 57888] = 0.f;  // 64-B zero guard
    }
}

// ---------------------------------------------------------------------------
// MFMA 3x3 conv, 16x8 px tile (128 px/block), 4 waves x 2 row-groups x MT=2.
// Every weight A-fragment feeds BOTH row-groups (2x weight-traffic reuse,
// same trick as dcn r15). Activation staged in 64-ch slices with chunk-XOR
// swizzle via global_load_lds; zero-guard for OOB halo. CIN=64: single stage
// (one barrier); CIN=128: 2 slices dbuf. grid = 72*4*NZ, XCD-chunked swizzle.
template<int CIN, int NZ, bool LRELU, bool ST_F32, bool ST_CHL>
__global__ __launch_bounds__(256, 3) void conv_mfma_k(
        const ushort* __restrict__ xin,      // [b][9216][CIN] bf16
        const ushort* __restrict__ wp,       // [CIN/32][9][4][CoutP][8]
        const float* __restrict__ bias,
        float* __restrict__ outf,            // NCHW fp32
        ushort* __restrict__ chl,            // ch-last bf16
        const ushort* __restrict__ zg,       // 64-B zero guard
        int CoutR, int CoutP, int ochs, int ocoff) {
    constexpr int SL = CIN / 64;
    __shared__ ushort s_act[SL][11520];       // [buf][180 px][8 chunks][8u] 23 KB

    int tid = threadIdx.x;
    int wv = tid >> 6, ln = tid & 63;
    int l15 = ln & 15, l4 = ln >> 4;

    constexpr int TOTAL = 72 * 4 * NZ;
    constexpr int CHUNK = TOTAL / 8;
    int bid = blockIdx.x;
    int nid = (bid & 7) * CHUNK + (bid >> 3);
    int zc = nid % NZ; int r1 = nid / NZ;
    int tile = r1 % 72; int b = r1 / 72;      // b-major banding
    int bx = (tile % 6) * 16, by = (tile / 6) * 8;
    int oc0 = zc * 32;

    const ushort* wlane = wp + ((size_t)l4 * CoutP + oc0 + l15) * 8;

    f32x4 acc[2][2];                          // [row-group][mt]
#pragma unroll
    for (int g = 0; g < 2; ++g)
#pragma unroll
        for (int mt = 0; mt < 2; ++mt)
            acc[g][mt] = (f32x4){0.f, 0.f, 0.f, 0.f};

    // stage one 64-ch slice: halo 10 rows x 18 cols, chunk-XOR swizzled
    auto STAGE = [&](int sl, int buf) {
        for (int i = tid; i < 1440; i += 256) {
            int P = i >> 3, s8 = i & 7;
            int q = s8 ^ (P & 7);             // inverse-swizzled source chunk
            int ry = by - 1 + P / 18, rx = bx - 1 + P % 18;
            const ushort* src = zg;
            if ((unsigned)ry < 96u && (unsigned)rx < 96u)
                src = xin + ((size_t)(b * 9216 + ry * 96 + rx) * CIN
                             + sl * 64 + q * 8);
            GL_LDS16(src, s_act[buf] + (size_t)i * 8);
        }
    };

    STAGE(0, 0);
    __syncthreads();
#pragma unroll
    for (int sl = 0; sl < SL; ++sl) {
        if (sl + 1 < SL) STAGE(sl + 1, (sl + 1) & 1);
#pragma unroll
        for (int cc2 = 0; cc2 < 2; ++cc2) {
            int c8 = cc2 * 4 + l4;
#pragma unroll
            for (int kk = 0; kk < 9; ++kk) {
                int ky = kk / 3, kx = kk % 3;
                int P0 = (wv * 2 + ky) * 18 + l15 + kx;   // row-group 0
                int P1 = P0 + 18;                          // row-group 1
                bf16x8 bf0 = *(const bf16x8*)(s_act[sl & (SL - 1)] +
                    ((size_t)(P0 * 8 + (c8 ^ (P0 & 7)))) * 8);
                bf16x8 bf1 = *(const bf16x8*)(s_act[sl & (SL - 1)] +
                    ((size_t)(P1 * 8 + (c8 ^ (P1 & 7)))) * 8);
#pragma unroll
                for (int mt = 0; mt < 2; ++mt) {
                    bf16x8 af = *(const bf16x8*)(wlane +
                        ((size_t)((sl * 2 + cc2) * 36 + kk * 4) * CoutP + mt * 16) * 8);
                    acc[0][mt] = __builtin_amdgcn_mfma_f32_16x16x32_bf16(
                        af, bf0, acc[0][mt], 0, 0, 0);
                    acc[1][mt] = __builtin_amdgcn_mfma_f32_16x16x32_bf16(
                        af, bf1, acc[1][mt], 0, 0, 0);
                }
            }
        }
        if (sl + 1 < SL) __syncthreads();
    }

#pragma unroll
    for (int g = 0; g < 2; ++g) {
        int gy = by + wv * 2 + g, gxp = bx + l15;
        size_t pxg = (size_t)b * 9216 + gy * 96 + gxp;
#pragma unroll
        for (int mt = 0; mt < 2; ++mt) {
            int ocb = oc0 + mt * 16 + l4 * 4;
            ushort hb[4];
#pragma unroll
            for (int r = 0; r < 4; ++r) {
                int oc = ocb + r;
                float v = acc[g][mt][r] + ((oc < CoutR) ? bias[oc] : 0.f);
                if (LRELU) v = (v >= 0.f) ? v : 0.1f * v;
                hb[r] = f2bf(v);
                if (ST_F32 && oc < CoutR)
                    outf[((size_t)b * CoutR + oc) * 9216 + gy * 96 + gxp] = v;
            }
            if (ST_CHL && ocb < CoutR) {
                uint2 pk;
                pk.x = (uint)hb[0] | ((uint)hb[1] << 16);
                pk.y = (uint)hb[2] | ((uint)hb[3] << 16);
                *(uint2*)(chl + pxg * ochs + ocoff + ocb) = pk;
            }
        }
    }
}

// ---------------------------------------------------------------------------
// Fused om-conv + DCNv2, 3-way split-K, 32-px band, LDS-landed gathers.
// (unchanged from r15 — proven: spill-free, weight reuse, 44 us)
__global__ __launch_bounds__(192, 2) void dcn_fused_k(
        const ushort* __restrict__ xoff,     // [b][px][64] ch-last bf16
        const ushort* __restrict__ xg1,      // [b][8][9216][8] f16
        const ushort* __restrict__ womp,     // [cc][kk][4][288][8] bf16
        const float* __restrict__ bpp,       // permuted om bias [288]
        const ushort* __restrict__ wdp,      // f16 [gkk*64+oc][8]
        const float* __restrict__ bd, ushort* __restrict__ chl,
        const ushort* __restrict__ zg) {
    __shared__ ushort s_x[816 * 8];           // halo band: 13,056 B
    __shared__ ushort s_zone[3 * 2 * 4 * 64 * 8];  // gather zone: 24,576 B
    __shared__ float s_red[2][2][64][17];
    int tid = threadIdx.x;
    int kq = tid >> 6, ln = tid & 63;
    int l15 = ln & 15, l4 = ln >> 4;
    int bid = blockIdx.x;                     // 0..1151
    int nid = (bid & 7) * 144 + (bid >> 3);   // XCD-chunked swizzle
    int pxb = nid % 288; int b = nid / 288;   // b-major banding
    int px0 = pxb * 32;
    int y = px0 / 96, x0 = px0 % 96;          // x0 in {0,32,64}

    // ---- stage xoff halo band (rows y-1..y+1, cols x0-1..x0+32) ----
    for (int i = tid; i < 816; i += 192) {
        int P = i >> 3, s8 = i & 7;
        int q = s8 ^ (P & 7);                 // inverse-swizzled source chunk
        int ry = y - 1 + P / 34, rx = x0 - 1 + P % 34;
        const ushort* src = zg;
        if ((unsigned)ry < 96u && (unsigned)rx < 96u)
            src = xoff + (((size_t)b * 9216 + ry * 96 + rx) * 64 + q * 8);
        GL_LDS16(src, s_x + (size_t)i * 8);
    }
    __syncthreads();

    f32x4 acc0[4], acc1[4];
#pragma unroll
    for (int mt = 0; mt < 4; ++mt) {
        acc0[mt] = (f32x4){0.f, 0.f, 0.f, 0.f};
        acc1[mt] = (f32x4){0.f, 0.f, 0.f, 0.f};
    }

    float cwb[2][4];                          // lerp weights, 1 step live

    // address calc + ISSUE 4 gathers-to-LDS for (step s, group gx)
    auto PREP = [&](int s, int gx, const f32x4& aom) {
        int st = kq * 6 + s;
        int gkk = st * 4 + l4;
        int g = gkk / 9, kk = gkk - g * 9;
        int bofs = st * 16 + l4 * 4;
        int xx = x0 + gx * 16 + l15;
        float oy = aom[0] + bpp[bofs];
        float ox = aom[1] + bpp[bofs + 1];
        float mm = 1.f / (1.f + __expf(-(aom[2] + bpp[bofs + 2])));
        float py = oy + (float)(y + kk / 3 - 1);
        float pxf = ox + (float)(xx + kk % 3 - 1);
        float yf = floorf(py), xf = floorf(pxf);
        float fy = py - yf, fx = pxf - xf;
        int iy0 = (int)yf, ix0 = (int)xf;
        int iy1 = iy0 + 1, ix1 = ix0 + 1;
        float vy0 = ((unsigned)iy0 < 96u) ? 1.f : 0.f;
        float vy1 = ((unsigned)iy1 < 96u) ? 1.f : 0.f;
        float vx0 = ((unsigned)ix0 < 96u) ? 1.f : 0.f;
        float vx1 = ((unsigned)ix1 < 96u) ? 1.f : 0.f;
        int r0 = min(max(iy0, 0), 95), r1 = min(max(iy1, 0), 95);
        int lb = min(max(ix0, 0), 94);
        // half-selects: which 16B cell (lb or lb+1) each x-corner lives in
        float h0 = (float)min(max(ix0 - lb, 0), 1);   // 1 only when ix0==95
        float h1 = (float)min(max(ix1 - lb, 0), 1);   // 0 only when ix0==-1
        float wx0 = (1.f - fx) * vx0, wx1 = fx * vx1;
        float xw0 = wx0 * (1.f - h0) + wx1 * (1.f - h1);
        float xw1 = wx0 * h0 + wx1 * h1;
        float rw0 = (1.f - fy) * vy0 * mm, rw1 = fy * vy1 * mm;
        cwb[gx][0] = rw0 * xw0; cwb[gx][1] = rw0 * xw1;
        cwb[gx][2] = rw1 * xw0; cwb[gx][3] = rw1 * xw1;
        const ushort* gp = xg1 + ((size_t)(b * 8 + g) * 9216) * 8;
        const ushort* p0 = gp + ((size_t)(r0 * 96 + lb)) * 8;
        const ushort* p1 = gp + ((size_t)(r1 * 96 + lb)) * 8;
        ushort* zb = s_zone + ((size_t)((kq * 2 + gx) * 4) * 64 + ln) * 8;
        GL_LDS16(p0,     zb);
        GL_LDS16(p0 + 8, zb + 64 * 8);
        GL_LDS16(p1,     zb + 128 * 8);
        GL_LDS16(p1 + 8, zb + 192 * 8);
    };

    // consume step s: drain gathers, lerp both groups, 8 MFMA on 4 shared af
    auto CONSUME2 = [&](int s) {
        asm volatile("s_waitcnt vmcnt(0)" ::: "memory");
        __builtin_amdgcn_sched_barrier(0);
        half8 bu[2];
#pragma unroll
        for (int gx = 0; gx < 2; ++gx) {
            const ushort* zb = s_zone + ((size_t)((kq * 2 + gx) * 4) * 64 + ln) * 8;
            union { int4v v; __half2 h2[4]; } a0, a1, b0c, b1c;
            a0.v  = *(const int4v*)zb;
            a1.v  = *(const int4v*)(zb + 64 * 8);
            b0c.v = *(const int4v*)(zb + 128 * 8);
            b1c.v = *(const int4v*)(zb + 192 * 8);
            __half2 w0 = __float2half2_rn(cwb[gx][0]);
            __half2 w1 = __float2half2_rn(cwb[gx][1]);
            __half2 w2 = __float2half2_rn(cwb[gx][2]);
            __half2 w3 = __float2half2_rn(cwb[gx][3]);
            union { __half2 h2[4]; half8 v; } buv;
#pragma unroll
            for (int j = 0; j < 4; ++j) {
                __half2 t = __hmul2(a0.h2[j], w0);
                t = __hfma2(a1.h2[j], w1, t);
                t = __hfma2(b0c.h2[j], w2, t);
                t = __hfma2(b1c.h2[j], w3, t);
                buv.h2[j] = t;
            }
            bu[gx] = buv.v;
        }
        int gkk = (kq * 6 + s) * 4 + l4;
#pragma unroll
        for (int mt = 0; mt < 4; ++mt) {
            half8 af = *(const half8*)(wdp +
                ((size_t)gkk * 64 + mt * 16 + l15) * 8);
            acc0[mt] = __builtin_amdgcn_mfma_f32_16x16x32_f16(
                af, bu[0], acc0[mt], 0, 0, 0);
            acc1[mt] = __builtin_amdgcn_mfma_f32_16x16x32_f16(
                af, bu[1], acc1[mt], 0, 0, 0);
        }
    };

    // s-major: om tiles (both groups, shared af) -> consume s-1 -> issue s
#pragma unroll
    for (int s = 0; s < 7; ++s) {
        f32x4 aom0 = (f32x4){0.f, 0.f, 0.f, 0.f};
        f32x4 aom1 = (f32x4){0.f, 0.f, 0.f, 0.f};
        if (s < 6) {
#pragma unroll
            for (int kk = 0; kk < 9; ++kk) {
                int ky = kk / 3, kx = kk % 3;
#pragma unroll
                for (int cc = 0; cc < 2; ++cc) {
                    int c8 = cc * 4 + l4;
                    int P0 = ky * 34 + l15 + kx;
                    int P1 = P0 + 16;
                    bf16x8 bf0 = *(const bf16x8*)(s_x +
                        ((size_t)(P0 * 8 + (c8 ^ (P0 & 7)))) * 8);
                    bf16x8 bf1 = *(const bf16x8*)(s_x +
                        ((size_t)(P1 * 8 + (c8 ^ (P1 & 7)))) * 8);
                    bf16x8 af = *(const bf16x8*)(womp +
                        ((size_t)(((cc * 9 + kk) * 4 + l4) * 288)
                         + (kq * 6 + s) * 16 + l15) * 8);
                    aom0 = __builtin_amdgcn_mfma_f32_16x16x32_bf16(
                        af, bf0, aom0, 0, 0, 0);
                    aom1 = __builtin_amdgcn_mfma_f32_16x16x32_bf16(
                        af, bf1, aom1, 0, 0, 0);
                }
            }
        }
        if (s >= 1) CONSUME2(s - 1);
        if (s < 6) {
            PREP(s, 0, aom0);
            PREP(s, 1, aom1);
        }
    }

    // 3-way split-K reduce: kq=1,2 write, kq=0 adds + stores
    if (kq) {
#pragma unroll
        for (int mt = 0; mt < 4; ++mt)
#pragma unroll
            for (int r = 0; r < 4; ++r) {
                s_red[kq - 1][0][ln][mt * 4 + r] = acc0[mt][r];
                s_red[kq - 1][1][ln][mt * 4 + r] = acc1[mt][r];
            }
    }
    __syncthreads();
    if (!kq) {
#pragma unroll
        for (int gx = 0; gx < 2; ++gx) {
            size_t pb = (size_t)b * 9216 + px0 + gx * 16 + l15;
#pragma unroll
            for (int mt = 0; mt < 4; ++mt) {
                ushort hb[4];
#pragma unroll
                for (int r = 0; r < 4; ++r) {
                    int oc = mt * 16 + l4 * 4 + r;
                    float a = gx ? acc1[mt][r] : acc0[mt][r];
                    float v = a + s_red[0][gx][ln][mt * 4 + r]
                            + s_red[1][gx][ln][mt * 4 + r] + bd[oc];
                    hb[r] = f2bf(v);
                }
                uint2 pk;
                pk.x = (uint)hb[0] | ((uint)hb[1] << 16);
                pk.y = (uint)hb[2] | ((uint)hb[3] << 16);
                *(uint2*)(chl + pb * 128 + mt * 16 + l4 * 4) = pk;
            }
        }
    }
}

// ---------------------------------------------------------------------------
extern "C" void kernel_launch(void* const* d_in, const int* in_sizes, int n_in,
                              void* d_out, int out_size, void* d_ws, size_t ws_size,
                              hipStream_t stream) {
    const float* src0  = (const float*)d_in[0];
    const float* src1  = (const float*)d_in[1];
    const float* l_off = (const float*)d_in[2];
    const float* l_fea = (const float*)d_in[3];
    const float* w1 = (const float*)d_in[4];   const float* b1 = (const float*)d_in[5];
    const float* w2 = (const float*)d_in[6];   const float* b2 = (const float*)d_in[7];
    const float* w3 = (const float*)d_in[8];   const float* b3 = (const float*)d_in[9];
    const float* wom = (const float*)d_in[10]; const float* bom = (const float*)d_in[11];
    const float* wd = (const float*)d_in[12];  const float* bd = (const float*)d_in[13];
    const float* wf = (const float*)d_in[14];  const float* bf = (const float*)d_in[15];

    // workspace schedule (lifetimes annotated)
    char* W = (char*)d_ws;
    ushort* xin1 = (ushort*)(W + 0);          //  9,437,184 B  live to conv1
    ushort* xin2 = (ushort*)(W + 9437184);    //  9,437,184 B  dead after conv2
    ushort* xoff = (ushort*)(W + 9437184);    //  4,718,592 B  over xin2; live to dcn
    ushort* xin3 = (ushort*)(W + 18874368);   //  4,718,592 B  dead after conv3
    ushort* xin4 = (ushort*)(W + 44826624);   //  9,437,184 B  [b][px][128]
    ushort* xg1  = (ushort*)(W + 54263808);   //  4,718,592 B  [b][8][px][8] f16
    ushort* w1p  = (ushort*)(W + 58982400);   // 147,456 B
    ushort* w2p  = (ushort*)(W + 59129856);   // 147,456 B
    ushort* w3p  = (ushort*)(W + 59277312);   //  73,728 B
    ushort* womp = (ushort*)(W + 59351040);   // 331,776 B (288-wide permuted)
    ushort* wdp  = (ushort*)(W + 59682816);   //  73,728 B (f16)
    ushort* wfp  = (ushort*)(W + 59756544);   // 147,456 B
    float*  bpp  = (float*)(W + 59904000);    //   1,152 B permuted om bias
    float*  zgrd = (float*)(W + 59905152);    //      64 B zero guard

    float* out_off = (float*)d_out;
    float* out_fea = out_off + (size_t)4 * 64 * 9216;

    // fused packs + prepack (z=3)
    pack_combo_k<<<dim3(144, 4, 4), 256, 0, stream>>>(
        src0, src1, l_off, l_fea, w1, w2, w3, wom, wd, wf, bom,
        xin1, xin2, xin4, xg1, w1p, w2p, w3p, womp, wdp, wfp, bpp, zgrd);

    const ushort* zg = (const ushort*)zgrd;
    // conv1: xin1 -> xin2[0:64] (lrelu, ch-last)  [16x8 tile, af reuse]
    conv_mfma_k<128, 2, true, false, true><<<576, 256, 0, stream>>>(
        xin1, w1p, b1, nullptr, xin2, zg, 64, 64, 128, 0);
    // conv2: xin2 -> xin3 (lrelu, ch-last)
    conv_mfma_k<128, 2, true, false, true><<<576, 256, 0, stream>>>(
        xin2, w2p, b2, nullptr, xin3, zg, 64, 64, 64, 0);
    // conv3: xin3 -> out_off (fp32 NCHW) + xoff (ch-last)
    conv_mfma_k<64, 2, true, true, true><<<576, 256, 0, stream>>>(
        xin3, w3p, b3, out_off, xoff, zg, 64, 64, 64, 0);
    // fused om-conv + DCN -> xin4[0:64]  (32-px band, LDS-landed gathers)
    dcn_fused_k<<<1152, 192, 0, stream>>>(xoff, xg1, womp, bpp, wdp, bd,
                                          xin4, zg);
    // fea conv: xin4 -> out_fea (fp32 NCHW, lrelu)
    conv_mfma_k<128, 2, true, true, false><<<576, 256, 0, stream>>>(
        xin4, wfp, bf, out_fea, nullptr, zg, 64, 64, 0, 0);
}